// Round 1
// baseline (176.944 us; speedup 1.0000x reference)
//
#include <hip/hip_runtime.h>

#define BN 4096
#define KD 256
#define TILE 128
#define BK 64

typedef short bf16x8 __attribute__((ext_vector_type(8)));
typedef float f32x4 __attribute__((ext_vector_type(4)));
typedef unsigned short ushort_t;

__device__ inline void async_load16(const void* g, void* l) {
    __builtin_amdgcn_global_load_lds((const __attribute__((address_space(1))) void*)g,
                                     (__attribute__((address_space(3))) void*)l,
                                     16, 0, 0);
}

__device__ inline ushort_t f2bf(float f) {
    union { float f; unsigned int u; } x;
    x.f = f;
    unsigned int u = x.u;
    // round-to-nearest-even
    unsigned int r = (u + 0x7fffu + ((u >> 16) & 1u)) >> 16;
    return (ushort_t)r;
}

// Kernel 0: fp32 row norms + bf16 (RTNE) copies of xs, xt.
// One wave per row (64 lanes x float4 = 256 elements).
__global__ __launch_bounds__(256) void norm_cvt(
        const float* __restrict__ xs, const float* __restrict__ xt,
        ushort_t* __restrict__ xsb, ushort_t* __restrict__ xtb,
        float* __restrict__ norms) {
    int w = threadIdx.x >> 6;
    int lane = threadIdx.x & 63;
    int row = blockIdx.x * 4 + w;              // 0..8191
    const float* src = (row < BN) ? xs + (size_t)row * KD
                                  : xt + (size_t)(row - BN) * KD;
    ushort_t* dst = (row < BN) ? xsb + (size_t)row * KD
                               : xtb + (size_t)(row - BN) * KD;
    float4 v = ((const float4*)src)[lane];
    float s = v.x * v.x + v.y * v.y + v.z * v.z + v.w * v.w;
#pragma unroll
    for (int off = 32; off > 0; off >>= 1) s += __shfl_xor(s, off, 64);
    if (lane == 0) norms[row] = s;
    ushort4 o;
    o.x = f2bf(v.x); o.y = f2bf(v.y); o.z = f2bf(v.z); o.w = f2bf(v.w);
    ((ushort4*)dst)[lane] = o;
}

// PASS 1: sum of distances per matrix (z=0: dxx, 1: dyy, 2: dxy) -> sums[z]
// PASS 2: sum over alphas of exp terms with sign/weight -> sums[3]
// Symmetric matrices (z<2): only bj>=bi tiles computed; off-diag weight 2.
template <int PASS>
__global__ __launch_bounds__(256) void mmd_gemm(
        const ushort_t* __restrict__ xsb, const ushort_t* __restrict__ xtb,
        const float* __restrict__ norms, double* __restrict__ sums) {
    const int z = blockIdx.z;
    const int bi = blockIdx.y;   // row tile
    const int bj = blockIdx.x;   // col tile
    if (z < 2 && bj < bi) return;

    const ushort_t* X = (z == 1) ? xtb : xsb;
    const ushort_t* Y = (z == 0) ? xsb : xtb;
    const float* nX = norms + ((z == 1) ? BN : 0);
    const float* nY = norms + ((z == 0) ? 0 : BN);

    const int tid = threadIdx.x;
    const int lane = tid & 63;
    const int w = tid >> 6;       // wave 0..3
    const int wr = w >> 1;        // wave row 0..1
    const int wc = w & 1;         // wave col 0..1
    const int m16 = lane & 15;
    const int q = lane >> 4;      // quad 0..3

    const int i0 = bi * TILE;
    const int j0 = bj * TILE;

    __shared__ ushort_t lA[TILE * BK];
    __shared__ ushort_t lB[TILE * BK];
    __shared__ float red[4];

    // pass-2 constant: u = 2^(d * nhb), nhb = -log2(e)/(4m)  (the alpha=2 term)
    float nhb = 0.0f;
    if (PASS == 2) {
        double mz = sums[z] / ((double)BN * (double)BN);
        nhb = (float)(-1.4426950408889634 / (4.0 * mz));
    }

    f32x4 acc[4][4] = {};

#pragma unroll
    for (int kk = 0; kk < KD; kk += BK) {
        __syncthreads();   // protect LDS from previous iteration's readers
#pragma unroll
        for (int t = 0; t < 4; ++t) {
            int rowblk = w * 4 + t;                 // 0..15 (8 rows each)
            int r = rowblk * 8 + (lane >> 3);       // tile row 0..127
            int cch = lane & 7;                     // dest chunk slot (16B)
            int gch = cch ^ (r & 7);                // swizzled source chunk
            const ushort_t* gA = X + (size_t)(i0 + r) * KD + (kk + gch * 8);
            const ushort_t* gB = Y + (size_t)(j0 + r) * KD + (kk + gch * 8);
            async_load16(gA, (char*)lA + rowblk * 1024);
            async_load16(gB, (char*)lB + rowblk * 1024);
        }
        __syncthreads();   // drain DMA before fragment reads

#pragma unroll
        for (int ks = 0; ks < 2; ++ks) {
            bf16x8 af[4], bfr[4];
            int kap = ks * 4 + q;                   // global 16B chunk in row
#pragma unroll
            for (int rg = 0; rg < 4; ++rg) {
                int rowa = wr * 64 + rg * 16 + m16;
                int posa = kap ^ (rowa & 7);
                af[rg] = *(const bf16x8*)&lA[rowa * BK + posa * 8];
                int rowb = wc * 64 + rg * 16 + m16;
                int posb = kap ^ (rowb & 7);
                bfr[rg] = *(const bf16x8*)&lB[rowb * BK + posb * 8];
            }
#pragma unroll
            for (int rg = 0; rg < 4; ++rg)
#pragma unroll
                for (int ng = 0; ng < 4; ++ng)
                    acc[rg][ng] = __builtin_amdgcn_mfma_f32_16x16x32_bf16(
                        af[rg], bfr[ng], acc[rg][ng], 0, 0, 0);
        }
    }

    // epilogue: C/D layout col = lane&15, row = (lane>>4)*4 + reg
    float nxv[16];
#pragma unroll
    for (int rg = 0; rg < 4; ++rg)
#pragma unroll
        for (int rr = 0; rr < 4; ++rr)
            nxv[rg * 4 + rr] = nX[i0 + wr * 64 + rg * 16 + q * 4 + rr];
    float nyv[4];
#pragma unroll
    for (int ng = 0; ng < 4; ++ng)
        nyv[ng] = nY[j0 + wc * 64 + ng * 16 + m16];

    float local = 0.0f;
#pragma unroll
    for (int rg = 0; rg < 4; ++rg) {
#pragma unroll
        for (int ng = 0; ng < 4; ++ng) {
#pragma unroll
            for (int rr = 0; rr < 4; ++rr) {
                int i = i0 + wr * 64 + rg * 16 + q * 4 + rr;
                int j = j0 + wc * 64 + ng * 16 + m16;
                float sq = nxv[rg * 4 + rr] + nyv[ng] - 2.0f * acc[rg][ng][rr];
                sq = fmaxf(sq, 0.0f);
                float d = sqrtf(sq);
                if (z < 2 && i == j) d = 0.0f;   // exact-zero diagonal (kills bf16 bias)
                if (PASS == 1) {
                    local += d;
                } else {
                    // sum over alphas {1/8,1/4,1/2,1,2}: u^16+u^8+u^4+u^2+u
                    float u = exp2f(d * nhb);
                    float u2 = u * u;
                    float u4 = u2 * u2;
                    float u8 = u4 * u4;
                    float u16 = u8 * u8;
                    local += u + u2 + u4 + u8 + u16;
                }
            }
        }
    }

#pragma unroll
    for (int off = 32; off > 0; off >>= 1) local += __shfl_xor(local, off, 64);
    if (lane == 0) red[w] = local;
    __syncthreads();
    if (tid == 0) {
        double bs = (double)red[0] + (double)red[1] + (double)red[2] + (double)red[3];
        double coef = (z < 2 && bi != bj) ? 2.0 : 1.0;
        if (PASS == 2 && z == 2) coef = -2.0;
        atomicAdd(&sums[PASS == 1 ? z : 3], coef * bs);
    }
}

__global__ void mmd_finalize(const double* __restrict__ sums, float* __restrict__ out) {
    double S = sums[3];
    double l = sqrt(S / ((double)BN * (double)(BN - 1)));
    float f = (float)l;
    if (!(f == f)) f = 0.0f;
    out[0] = f;
}

extern "C" void kernel_launch(void* const* d_in, const int* in_sizes, int n_in,
                              void* d_out, int out_size, void* d_ws, size_t ws_size,
                              hipStream_t stream) {
    const float* xs = (const float*)d_in[0];
    const float* xt = (const float*)d_in[1];
    float* out = (float*)d_out;

    char* ws = (char*)d_ws;
    double* sums = (double*)ws;                         // 4 doubles (32B used, 64 reserved)
    float* norms = (float*)(ws + 64);                   // 8192 floats = 32 KB
    ushort_t* xsb = (ushort_t*)(ws + 64 + 32768);       // 2 MB
    ushort_t* xtb = xsb + (size_t)BN * KD;              // 2 MB

    size_t need = 64 + 32768 + 2 * (size_t)BN * KD * sizeof(ushort_t);
    if (ws_size < need) {
        // diagnostic: distinctive output (-6.015e0 pattern) so the failure is identifiable
        hipMemsetAsync(d_out, 0xC0, 4, stream);
        return;
    }

    hipMemsetAsync(d_ws, 0, 64, stream);
    norm_cvt<<<2048, 256, 0, stream>>>(xs, xt, xsb, xtb, norms);
    dim3 g(32, 32, 3);
    mmd_gemm<1><<<g, 256, 0, stream>>>(xsb, xtb, norms, sums);
    mmd_gemm<2><<<g, 256, 0, stream>>>(xsb, xtb, norms, sums);
    mmd_finalize<<<1, 1, 0, stream>>>(sums, out);
}